// Round 12
// baseline (427.564 us; speedup 1.0000x reference)
//
#include <hip/hip_runtime.h>

// Sliding-window attention, MI355X/gfx950. Round 17.
// Pipeline: prep_fused -> m97 GEMM +T1 (qkv) -> V transpose -> flash
// windowed attention (R10 pipeline + R16 DPP softmax + R17 bv-hoist)
// -> m97 GEMM +T1 fp32.
//
// LEDGER: R16 = best (411.1us). 256^2 GEMM dead on this shape (R11-R13
// spill at the 2-wave/SIMD 256-reg boundary). attn DS-pipe is the tile-loop
// bottleneck: 56 b128 reads + 64 b16 writes per wave per tile.
// R17 change (attn only, math-exact): hoist the 16 V-fragment b128 reads
// out of the mi loop (bvf[4][4], read once per tile after barD, held in
// 64 VGPRs, reused by both PV halves). DS reads 56 -> 40 per tile (-29%).
// MFMA issue order unchanged (mi, ksv, di) => bit-identical accumulation.

typedef unsigned short u16;
typedef unsigned int u32;
typedef __attribute__((ext_vector_type(8))) short bf16x8;   // 8 x bf16 (4 VGPRs)
typedef __attribute__((ext_vector_type(4))) float f32x4;

__device__ __forceinline__ float bf2f(u16 v) {
  union { u32 u; float f; } t; t.u = ((u32)v) << 16; return t.f;
}
__device__ __forceinline__ u16 f2bf(float f) {
  union { float f; u32 u; } t; t.f = f;
  u32 u = t.u + 0x7fffu + ((t.u >> 16) & 1u);   // RNE
  return (u16)(u >> 16);
}
__device__ __forceinline__ void g2lds16(const void* g, void* l) {
  __builtin_amdgcn_global_load_lds((const __attribute__((address_space(1))) void*)g,
                                   (__attribute__((address_space(3))) void*)l,
                                   16, 0, 0);
}

// 16-lane (one DPP row) butterfly reduce; all lanes end with the row result.
__device__ __forceinline__ float row16_max(float x) {
  union { float f; int i; } a, b;
  a.f = x; b.i = __builtin_amdgcn_update_dpp(0, a.i, 0xB1, 0xF, 0xF, false);
  x = fmaxf(x, b.f);
  a.f = x; b.i = __builtin_amdgcn_update_dpp(0, a.i, 0x4E, 0xF, 0xF, false);
  x = fmaxf(x, b.f);
  a.f = x; b.i = __builtin_amdgcn_update_dpp(0, a.i, 0x141, 0xF, 0xF, false);
  x = fmaxf(x, b.f);
  a.f = x; b.i = __builtin_amdgcn_update_dpp(0, a.i, 0x140, 0xF, 0xF, false);
  return fmaxf(x, b.f);
}
__device__ __forceinline__ float row16_sum(float x) {
  union { float f; int i; } a, b;
  a.f = x; b.i = __builtin_amdgcn_update_dpp(0, a.i, 0xB1, 0xF, 0xF, false);
  x += b.f;
  a.f = x; b.i = __builtin_amdgcn_update_dpp(0, a.i, 0x4E, 0xF, 0xF, false);
  x += b.f;
  a.f = x; b.i = __builtin_amdgcn_update_dpp(0, a.i, 0x141, 0xF, 0xF, false);
  x += b.f;
  a.f = x; b.i = __builtin_amdgcn_update_dpp(0, a.i, 0x140, 0xF, 0xF, false);
  return x + b.f;
}

// ---------------------------------------------------------------------------
// Fused prep (one launch):
//   blocks [0, 8192):        x [16384][1024] fp32 -> bf16 flat
//   blocks [8192, 11264):    w_qkv [1024][3072] -> wqkvT [3072][1024] bf16
//   blocks [11264, 12288):   w_o   [1024][1024] -> woT   [1024][1024] bf16
// ---------------------------------------------------------------------------
__global__ __launch_bounds__(256) void prep_fused(
    const float* __restrict__ xf, u16* __restrict__ xb,
    const float* __restrict__ wqkv, u16* __restrict__ wqkvT,
    const float* __restrict__ wo, u16* __restrict__ woT) {
  __shared__ u16 tile[32][33];
  const int b = blockIdx.x;
  if (b < 8192) {
    size_t i = ((size_t)b * 256 + threadIdx.x) * 8;
    float4 a = *(const float4*)(xf + i);
    float4 c = *(const float4*)(xf + i + 4);
    u16 o[8] = { f2bf(a.x), f2bf(a.y), f2bf(a.z), f2bf(a.w),
                 f2bf(c.x), f2bf(c.y), f2bf(c.z), f2bf(c.w) };
    *(bf16x8*)(xb + i) = *(bf16x8*)o;
    return;
  }
  const float* in;
  u16* out;
  int R = 1024, C, c0, r0;
  if (b < 11264) {
    int idx = b - 8192;                 // was grid (96, 32)
    in = wqkv; out = wqkvT; C = 3072;
    c0 = (idx % 96) * 32; r0 = (idx / 96) * 32;
  } else {
    int idx = b - 11264;                // was grid (32, 32)
    in = wo; out = woT; C = 1024;
    c0 = (idx % 32) * 32; r0 = (idx / 32) * 32;
  }
  int tx = threadIdx.x & 31, ty = threadIdx.x >> 5;
#pragma unroll
  for (int i = 0; i < 32; i += 8)
    tile[ty + i][tx] = f2bf(in[(size_t)(r0 + ty + i) * C + c0 + tx]);
  __syncthreads();
#pragma unroll
  for (int i = 0; i < 32; i += 8)
    out[(size_t)(c0 + ty + i) * R + r0 + tx] = tile[tx][ty + i];
}

// ---------------------------------------------------------------------------
// V part of qkv [16384][3072] -> Vt [bh=512][d=64][t=512]   (bf16)
// ---------------------------------------------------------------------------
__global__ __launch_bounds__(256) void transpose_v(
    const u16* __restrict__ qkv, u16* __restrict__ vt) {
  __shared__ u16 tile[32][33];
  int bh = blockIdx.z, bn = bh >> 4, h = bh & 15;
  int t0 = blockIdx.x * 32, d0 = blockIdx.y * 32;
  int tx = threadIdx.x & 31, ty = threadIdx.x >> 5;
  const u16* src = qkv + (size_t)(bn * 512) * 3072 + 2048 + h * 64;
#pragma unroll
  for (int i = 0; i < 32; i += 8)
    tile[ty + i][tx] = src[(size_t)(t0 + ty + i) * 3072 + d0 + tx];
  __syncthreads();
  u16* dst = vt + ((size_t)bh * 64 + d0) * 512 + t0;
#pragma unroll
  for (int i = 0; i < 32; i += 8)
    dst[(size_t)(ty + i) * 512 + tx] = tile[tx][ty + i];
}

// ---------------------------------------------------------------------------
// C[M,N] = A[M,K](bf16) * Bt[N,K]^T(bf16) + bias[N](fp32); OutT u16|float.
// m97 structure: 128x128 tile, BK=32, 2x2 waves of 64x64, global_load_lds
// w=16, T1 XCD swizzle (grid.x*grid.y % 8 == 0). R10/R15-exact (verified).
// ---------------------------------------------------------------------------
template <typename OutT>
__global__ __launch_bounds__(256, 2) void gemm_bt_bias(
    const u16* __restrict__ A, const u16* __restrict__ Bt,
    const float* __restrict__ bias, OutT* __restrict__ C,
    int M, int N, int K) {
  __shared__ __align__(16) u16 As[128 * 32];
  __shared__ __align__(16) u16 Bs[128 * 32];
  const int tid = threadIdx.x;
  const int wave = tid >> 6, lane = tid & 63;
  const int quad = lane >> 4, l16 = lane & 15;

  // T1: dispatch index -> logical block, contiguous chunk per XCD.
  const int nbx = gridDim.x;
  const int ntot = nbx * gridDim.y;
  const int flat = blockIdx.y * nbx + blockIdx.x;
  const int swz = (flat & 7) * (ntot >> 3) + (flat >> 3);
  const int m0 = (swz / nbx) * 128, n0 = (swz % nbx) * 128;
  const int wm = (wave >> 1) * 64, wn = (wave & 1) * 64;

  f32x4 acc[4][4] = {};

  int e0 = (wave * 512) + lane * 8;   // chunk 0 element offset in 128x32 tile
  int e1 = 2048 + e0;                 // chunk 1
  int rA0 = e0 >> 5, cA0 = e0 & 31;
  int rA1 = e1 >> 5, cA1 = e1 & 31;
  const u16* ga0 = A + (size_t)(m0 + rA0) * K + cA0;
  const u16* ga1 = A + (size_t)(m0 + rA1) * K + cA1;
  const u16* gb0 = Bt + (size_t)(n0 + rA0) * K + cA0;
  const u16* gb1 = Bt + (size_t)(n0 + rA1) * K + cA1;
  u16* As0 = As + (size_t)wave * 512;
  u16* As1 = As0 + 2048;
  u16* Bs0 = Bs + (size_t)wave * 512;
  u16* Bs1 = Bs0 + 2048;

  for (int k0 = 0; k0 < K; k0 += 32) {
    g2lds16(ga0 + k0, As0);
    g2lds16(ga1 + k0, As1);
    g2lds16(gb0 + k0, Bs0);
    g2lds16(gb1 + k0, Bs1);
    __syncthreads();
    bf16x8 a[4], b[4];
#pragma unroll
    for (int mi = 0; mi < 4; ++mi)
      a[mi] = *(const bf16x8*)(As + (wm + mi * 16 + l16) * 32 + quad * 8);
#pragma unroll
    for (int ni = 0; ni < 4; ++ni)
      b[ni] = *(const bf16x8*)(Bs + (wn + ni * 16 + l16) * 32 + quad * 8);
#pragma unroll
    for (int mi = 0; mi < 4; ++mi)
#pragma unroll
      for (int ni = 0; ni < 4; ++ni)
        acc[mi][ni] = __builtin_amdgcn_mfma_f32_16x16x32_bf16(a[mi], b[ni], acc[mi][ni], 0, 0, 0);
    __syncthreads();
  }

  // epilogue: C/D layout col=l16, row=quad*4+reg
#pragma unroll
  for (int ni = 0; ni < 4; ++ni) {
    int col = n0 + wn + ni * 16 + l16;
    float bv = bias[col];
#pragma unroll
    for (int mi = 0; mi < 4; ++mi) {
      int row = m0 + wm + mi * 16 + quad * 4;
#pragma unroll
      for (int r = 0; r < 4; ++r) {
        float v = acc[mi][ni][r] + bv;
        if constexpr (sizeof(OutT) == 2)
          C[(size_t)(row + r) * N + col] = f2bf(v);
        else
          C[(size_t)(row + r) * N + col] = v;
      }
    }
  }
}

// ---------------------------------------------------------------------------
// Windowed causal flash attention. Grid (qt=4, h=16, bn=32), 256 threads.
// R10 counted-vmcnt pipeline + R16 DPP softmax + R17 bv-hoist (V fragments
// read once per tile into 64 VGPRs, reused by both PV halves).
// ---------------------------------------------------------------------------
__global__ __launch_bounds__(256, 2) void attn_win(
    const u16* __restrict__ qkv, const u16* __restrict__ vt,
    u16* __restrict__ attn) {
  __shared__ __align__(16) u16 Ks[128 * 64];
  __shared__ __align__(16) u16 Vs[64 * 128];
  __shared__ __align__(16) u16 Ps[4][16 * 128];

  const int qt = blockIdx.x, h = blockIdx.y, bn = blockIdx.z;
  const int bh = bn * 16 + h;
  const int tid = threadIdx.x;
  const int wave = tid >> 6, lane = tid & 63;
  const int quad = lane >> 4, l16 = lane & 15;
  const int t0 = bn * 512 + qt * 128;

  bf16x8 aq[2][2];
#pragma unroll
  for (int mi = 0; mi < 2; ++mi)
#pragma unroll
    for (int ks = 0; ks < 2; ++ks)
      aq[mi][ks] = *(const bf16x8*)(
          qkv + (size_t)(t0 + wave * 32 + mi * 16 + l16) * 3072 + h * 64 + ks * 32 + quad * 8);

  const int rk0 = tid >> 3, ck0 = tid & 7;
  const int rv0 = tid >> 4, cv0 = tid & 15;

#define STAGE_K(JT)                                                           \
  {                                                                           \
    const int tk_ = bn * 512 + (JT) * 128;                                    \
    _Pragma("unroll")                                                         \
    for (int it = 0; it < 4; ++it) {                                          \
      int rk = it * 32 + rk0;                                                 \
      const u16* gk = qkv + (size_t)(tk_ + rk) * 3072 + 1024 + h * 64 +       \
                      ((ck0 ^ (rk & 7)) * 8);                                 \
      g2lds16(gk, Ks + (size_t)(it * 256 + wave * 64) * 8);                   \
    }                                                                         \
  }
#define STAGE_V(JT)                                                           \
  {                                                                           \
    _Pragma("unroll")                                                         \
    for (int it = 0; it < 4; ++it) {                                          \
      int rv = it * 16 + rv0;                                                 \
      const u16* gv = vt + ((size_t)bh * 64 + rv) * 512 + (JT) * 128 +        \
                      ((cv0 ^ (rv & 15)) * 8);                                \
      g2lds16(gv, Vs + (size_t)(it * 256 + wave * 64) * 8);                   \
    }                                                                         \
  }

  STAGE_K(0);
  STAGE_V(0);
  asm volatile("s_waitcnt vmcnt(4)" ::: "memory");
  __builtin_amdgcn_s_barrier();
  __builtin_amdgcn_sched_barrier(0);

  float mrun[2][4], lrun[2][4];        // lrun = per-lane PARTIAL sums (R16)
  f32x4 o[2][4] = {};
#pragma unroll
  for (int mi = 0; mi < 2; ++mi)
#pragma unroll
    for (int r = 0; r < 4; ++r) { mrun[mi][r] = -1e30f; lrun[mi][r] = 0.f; }

  const float cexp = 0.18033688011112042f;  // (1/sqrt(64)) * log2(e)

  u16* pw = &Ps[wave][0];

  for (int j = 0; j <= qt; ++j) {
    f32x4 s[2][8] = {};
    __builtin_amdgcn_s_setprio(1);
#pragma unroll
    for (int ks = 0; ks < 2; ++ks) {
#pragma unroll
      for (int ni = 0; ni < 8; ++ni) {
        int n = ni * 16 + l16;
        bf16x8 bk = *(const bf16x8*)(Ks + n * 64 + (((ks * 4 + quad) ^ (n & 7)) * 8));
        s[0][ni] = __builtin_amdgcn_mfma_f32_16x16x32_bf16(aq[0][ks], bk, s[0][ni], 0, 0, 0);
        s[1][ni] = __builtin_amdgcn_mfma_f32_16x16x32_bf16(aq[1][ks], bk, s[1][ni], 0, 0, 0);
      }
    }
    __builtin_amdgcn_s_setprio(0);

    __builtin_amdgcn_s_barrier();
    __builtin_amdgcn_sched_barrier(0);
    if (j < qt) STAGE_K(j + 1);

    // ---- online softmax (C layout: col=l16, row=quad*4+r) ----
    const bool diag = (j == qt);
#pragma unroll
    for (int mi = 0; mi < 2; ++mi) {
#pragma unroll
      for (int r = 0; r < 4; ++r) {
        int m = wave * 32 + mi * 16 + quad * 4 + r;
        float rmax = -1e30f;
#pragma unroll
        for (int ni = 0; ni < 8; ++ni) {
          float v = s[mi][ni][r] * cexp;
          if (diag && (ni * 16 + l16 > m)) v = -1e30f;
          s[mi][ni][r] = v;
          rmax = fmaxf(rmax, v);
        }
        rmax = row16_max(rmax);                    // DPP butterfly (R16)
        float mnew = fmaxf(mrun[mi][r], rmax);
        float alpha = exp2f(mrun[mi][r] - mnew);
        mrun[mi][r] = mnew;
        float rsum = 0.f;
#pragma unroll
        for (int ni = 0; ni < 8; ++ni) {
          float pv = exp2f(s[mi][ni][r] - mnew);
          s[mi][ni][r] = pv;
          rsum += pv;
        }
        lrun[mi][r] = lrun[mi][r] * alpha + rsum;  // partial (no reduce)
#pragma unroll
        for (int di = 0; di < 4; ++di) o[mi][di][r] *= alpha;
      }
    }

    if (j < qt) { asm volatile("s_waitcnt vmcnt(4)" ::: "memory"); }
    else        { asm volatile("s_waitcnt vmcnt(0)" ::: "memory"); }
    __builtin_amdgcn_s_barrier();
    __builtin_amdgcn_sched_barrier(0);

    // ---- R17: V fragments for this tile, read ONCE (reused by both mi) ----
    bf16x8 bvf[4][4];
#pragma unroll
    for (int ksv = 0; ksv < 4; ++ksv)
#pragma unroll
      for (int di = 0; di < 4; ++di) {
        int n = di * 16 + l16;
        bvf[ksv][di] = *(const bf16x8*)(Vs + n * 128 + (((ksv * 4 + quad) ^ (n & 15)) * 8));
      }

#pragma unroll
    for (int mi = 0; mi < 2; ++mi) {
#pragma unroll
      for (int ni = 0; ni < 8; ++ni)
#pragma unroll
        for (int r = 0; r < 4; ++r) {
          int row = quad * 4 + r;
          int col = ni * 16 + l16;
          int phys = (col >> 3) ^ row;
          pw[row * 128 + phys * 8 + (col & 7)] = f2bf(s[mi][ni][r]);
        }

      __builtin_amdgcn_s_setprio(1);
#pragma unroll
      for (int ksv = 0; ksv < 4; ++ksv) {
        bf16x8 ap = *(const bf16x8*)(pw + l16 * 128 + (((ksv * 4 + quad) ^ l16) * 8));
#pragma unroll
        for (int di = 0; di < 4; ++di)
          o[mi][di] = __builtin_amdgcn_mfma_f32_16x16x32_bf16(ap, bvf[ksv][di], o[mi][di], 0, 0, 0);
      }
      __builtin_amdgcn_s_setprio(0);
    }

    asm volatile("s_waitcnt vmcnt(0)" ::: "memory");
    __builtin_amdgcn_s_barrier();
    __builtin_amdgcn_sched_barrier(0);
    if (j < qt) STAGE_V(j + 1);
  }
#undef STAGE_K
#undef STAGE_V

  // ---- epilogue: reduce l partials once, then O / l -> attn (bf16) ----
#pragma unroll
  for (int mi = 0; mi < 2; ++mi)
#pragma unroll
    for (int r = 0; r < 4; ++r) {
      float inv = 1.0f / row16_sum(lrun[mi][r]);   // DPP reduce (R16)
      int trow = t0 + wave * 32 + mi * 16 + quad * 4 + r;
#pragma unroll
      for (int di = 0; di < 4; ++di)
        attn[(size_t)trow * 1024 + h * 64 + di * 16 + l16] = f2bf(o[mi][di][r] * inv);
    }
}

// ---------------------------------------------------------------------------
extern "C" void kernel_launch(void* const* d_in, const int* in_sizes, int n_in,
                              void* d_out, int out_size, void* d_ws, size_t ws_size,
                              hipStream_t stream) {
  (void)in_sizes; (void)n_in; (void)out_size; (void)ws_size;
  const float* x     = (const float*)d_in[0];   // [16384][1024] fp32
  const float* w_qkv = (const float*)d_in[1];   // [1024][3072] fp32
  const float* b_qkv = (const float*)d_in[2];   // [3072] fp32
  const float* w_o   = (const float*)d_in[3];   // [1024][1024] fp32
  const float* b_o   = (const float*)d_in[4];   // [1024] fp32
  float* out = (float*)d_out;                   // [16384][1024] fp32

  char* ws = (char*)d_ws;
  u16* qkv   = (u16*)(ws + 0);            // 96 MB
  u16* vtb   = (u16*)(ws + 100663296);    // 32 MB
  u16* attnb = (u16*)(ws + 134217728);    // 32 MB
  u16* xb    = (u16*)(ws + 167772160);    // 32 MB
  u16* wqkvT = (u16*)(ws + 201326592);    // 6 MB
  u16* woT   = (u16*)(ws + 207618048);    // 2 MB  (total 200 MB)

  prep_fused<<<12288, 256, 0, stream>>>(x, xb, w_qkv, wqkvT, w_o, woT);
  gemm_bt_bias<u16><<<dim3(24, 128), 256, 0, stream>>>(
      xb, wqkvT, b_qkv, qkv, 16384, 3072, 1024);
  transpose_v<<<dim3(16, 2, 512), 256, 0, stream>>>(qkv, vtb);
  attn_win<<<dim3(4, 16, 32), 256, 0, stream>>>(qkv, vtb, attnb);
  gemm_bt_bias<float><<<dim3(8, 128), 256, 0, stream>>>(
      attnb, woT, b_o, out, 16384, 1024, 1024);
}